// Round 8
// baseline (165.439 us; speedup 1.0000x reference)
//
#include <hip/hip_runtime.h>
#include <hip/hip_bf16.h>

typedef __bf16 bf16_t;
typedef __attribute__((ext_vector_type(8))) __bf16 bf16x8;
typedef __attribute__((ext_vector_type(4))) float f32x4;

#define KDIM 1152
#define NDIM 1152
#define BMB 64                        /* block rows (2 waves of 32) */
#define BN 192
#define NTILES 6                      /* 1152/192 */
#define SLAB_BYTES 12288              /* BN*32*2: one k-32 half-slab */
#define TILE_BYTES (36 * SLAB_BYTES)  /* per n-tile panel (k fastest) */
#define NH 36                         /* k-halves of 32 */

// Weff panel, fragment-contiguous per n-tile (BN=192) — unchanged (proven):
//   byte(n,k) = tile*TILE + (k>>5)*12288 + (nin>>4)*1024 + ((k>>3)&3)*256
//               + (nin&15)*16 + (k&7)*2     (tile = n/192, nin = n%192)
// => a wave's B-fragment (ni, k-half h) is 16B/lane contiguous at
//    tile*TILE + h*12288 + (wn*6+ni)*1024 + (lane>>4)*256 + (lane&15)*16
__global__ void build_wb(const float* __restrict__ W,
                         const float* __restrict__ bvec,
                         bf16_t* __restrict__ Bm,
                         float* __restrict__ bias)
{
    const int t = blockIdx.x * blockDim.x + threadIdx.x;
    if (t < NDIM) {
        const int o = t / 9, p = t - o * 9;
        bias[t] = bvec[p * 128 + o];
    }
    const int c = t & 127;
    const int o = (t >> 7) & 127;
    const int p = t >> 14;
    if (p >= 9) return;
    const int r = p / 3, cc = p - r * 3;
    float eff[3][3] = {{0.f,0.f,0.f},{0.f,0.f,0.f},{0.f,0.f,0.f}};
    const float* w = W + (size_t)((p * 128 + o) * 128 + c) * 9;
    #pragma unroll
    for (int i = 0; i < 3; ++i) {
        const int a = (2 + r + i) / 3;
        #pragma unroll
        for (int j = 0; j < 3; ++j) {
            const int bb = (2 + cc + j) / 3;
            eff[a][bb] += w[i * 3 + j];
        }
    }
    const int n = o * 9 + p;
    const int tile = n / BN;
    const int nin = n - tile * BN;
    #pragma unroll
    for (int a = 0; a < 3; ++a)
        #pragma unroll
        for (int bb = 0; bb < 3; ++bb) {
            const int k = c * 9 + a * 3 + bb;
            const size_t idx = (size_t)tile * (TILE_BYTES / 2)
                             + (k >> 5) * (SLAB_BYTES / 2)
                             + (nin >> 4) * 512 + ((k >> 3) & 3) * 128
                             + (nin & 15) * 8 + (k & 7);
            Bm[idx] = (bf16_t)eff[a][bb];
        }
}

// out[16384,1152] = X(fp32->bf16 in-reg) * Weff(bf16) + bias.
// BARRIER-FREE dataflow GEMM: no LDS, no __syncthreads, no inline asm.
// Block 64x192 = 4 waves (2m x 2n); wave tile 32x96 (acc 2x6 = 48 VGPR).
// A and B fragments loaded global->reg with a hand-unrolled 2-stage
// (even/odd k-half) register pipeline; compiler owns all s_waitcnt.
// B panel (2.65 MB) is L2-resident; waves free-run and hide each other's
// latency (12 waves/CU at <=170 VGPR).
__launch_bounds__(256, 3)
__global__ void ind_gemm(const float* __restrict__ X,
                         const bf16_t* __restrict__ Bm,
                         const float* __restrict__ bias,
                         float* __restrict__ out)
{
    const int tid = threadIdx.x;
    const int lane = tid & 63;
    const int wid = tid >> 6;
    const int wm = wid >> 1;
    const int wn = wid & 1;

    // XCD swizzle: 1536 blocks = 192/XCD; within an XCD, consecutive blocks
    // share one m-panel across the 6 n-tiles (A reuse in that XCD's L2).
    const int bid = blockIdx.x;
    const int swz = (bid & 7) * 192 + (bid >> 3);
    const int mt = swz / NTILES;
    const int nt = swz - mt * NTILES;
    const int m0 = mt * BMB;

    // A: row = m0 + wm*32 + mi*16 + (lane&15); k(h) = h*32 + (lane>>4)*8
    const float* a_base = X + (size_t)(m0 + wm * 32 + (lane & 15)) * KDIM
                            + ((lane >> 4) * 8);
    const float* a_mi0 = a_base;
    const float* a_mi1 = a_base + (size_t)16 * KDIM;

    // B: fragment base for this wave/lane within the n-tile panel
    const char* b_base = (const char*)Bm + (size_t)nt * TILE_BYTES
                       + wn * 6144 + (lane >> 4) * 256 + (lane & 15) * 16;

    f32x4 acc[2][6];
    #pragma unroll
    for (int i = 0; i < 2; ++i)
        #pragma unroll
        for (int j = 0; j < 6; ++j)
            acc[i][j] = (f32x4){0.f, 0.f, 0.f, 0.f};

    // Two register stages (even/odd k-half), all statically indexed.
    f32x4 a0_0l, a0_0h, a0_1l, a0_1h;   // stage 0: A mi=0/1, low/high f32x4
    f32x4 a1_0l, a1_0h, a1_1l, a1_1h;   // stage 1
    bf16x8 b0_[6], b1_[6];

    #define LOAD_S0(H) do {                                                 \
        const float* ap0_ = a_mi0 + (H) * 32;                               \
        const float* ap1_ = a_mi1 + (H) * 32;                               \
        a0_0l = *(const f32x4*)(ap0_);  a0_0h = *(const f32x4*)(ap0_ + 4);  \
        a0_1l = *(const f32x4*)(ap1_);  a0_1h = *(const f32x4*)(ap1_ + 4);  \
        const char* bp_ = b_base + (size_t)(H) * SLAB_BYTES;                \
        _Pragma("unroll")                                                   \
        for (int j_ = 0; j_ < 6; ++j_)                                      \
            b0_[j_] = *(const bf16x8*)(bp_ + j_ * 1024);                    \
    } while (0)

    #define LOAD_S1(H) do {                                                 \
        const float* ap0_ = a_mi0 + (H) * 32;                               \
        const float* ap1_ = a_mi1 + (H) * 32;                               \
        a1_0l = *(const f32x4*)(ap0_);  a1_0h = *(const f32x4*)(ap0_ + 4);  \
        a1_1l = *(const f32x4*)(ap1_);  a1_1h = *(const f32x4*)(ap1_ + 4);  \
        const char* bp_ = b_base + (size_t)(H) * SLAB_BYTES;                \
        _Pragma("unroll")                                                   \
        for (int j_ = 0; j_ < 6; ++j_)                                      \
            b1_[j_] = *(const bf16x8*)(bp_ + j_ * 1024);                    \
    } while (0)

    #define CVT8(DST, LO, HI) do {                                          \
        _Pragma("unroll")                                                   \
        for (int j_ = 0; j_ < 4; ++j_) {                                    \
            DST[j_]     = (__bf16)LO[j_];                                   \
            DST[4 + j_] = (__bf16)HI[j_];                                   \
        } } while (0)

    #define COMPUTE_S0() do {                                               \
        bf16x8 af0_, af1_;                                                  \
        CVT8(af0_, a0_0l, a0_0h);                                           \
        CVT8(af1_, a0_1l, a0_1h);                                           \
        _Pragma("unroll")                                                   \
        for (int j_ = 0; j_ < 6; ++j_) {                                    \
            acc[0][j_] = __builtin_amdgcn_mfma_f32_16x16x32_bf16(           \
                af0_, b0_[j_], acc[0][j_], 0, 0, 0);                        \
            acc[1][j_] = __builtin_amdgcn_mfma_f32_16x16x32_bf16(           \
                af1_, b0_[j_], acc[1][j_], 0, 0, 0);                        \
        } } while (0)

    #define COMPUTE_S1() do {                                               \
        bf16x8 af0_, af1_;                                                  \
        CVT8(af0_, a1_0l, a1_0h);                                           \
        CVT8(af1_, a1_1l, a1_1h);                                           \
        _Pragma("unroll")                                                   \
        for (int j_ = 0; j_ < 6; ++j_) {                                    \
            acc[0][j_] = __builtin_amdgcn_mfma_f32_16x16x32_bf16(           \
                af0_, b1_[j_], acc[0][j_], 0, 0, 0);                        \
            acc[1][j_] = __builtin_amdgcn_mfma_f32_16x16x32_bf16(           \
                af1_, b1_[j_], acc[1][j_], 0, 0, 0);                        \
        } } while (0)

    // ---- 2-stage register pipeline over 36 k-halves ----
    LOAD_S0(0);
    LOAD_S1(1);
    #pragma unroll 1
    for (int t2 = 0; t2 < 17; ++t2) {
        const int h = 2 * t2;
        COMPUTE_S0();
        LOAD_S0(h + 2);
        COMPUTE_S1();
        LOAD_S1(h + 3);
    }
    COMPUTE_S0();   // h = 34
    COMPUTE_S1();   // h = 35

    #undef LOAD_S0
    #undef LOAD_S1
    #undef CVT8
    #undef COMPUTE_S0
    #undef COMPUTE_S1

    // ---- epilogue: C/D col=lane&15, row=(lane>>4)*4+reg ----
    const int orow = (lane >> 4) * 4;
    const int ocol = lane & 15;
    const int gn0 = nt * BN + wn * 96 + ocol;
    #pragma unroll
    for (int ni = 0; ni < 6; ++ni) {
        const float bv = bias[gn0 + ni * 16];
        #pragma unroll
        for (int mi = 0; mi < 2; ++mi) {
            float* po = out + (size_t)(m0 + wm * 32 + mi * 16 + orow) * NDIM
                            + gn0 + ni * 16;
            #pragma unroll
            for (int r = 0; r < 4; ++r)
                po[(size_t)r * NDIM] = acc[mi][ni][r] + bv;
        }
    }
}

extern "C" void kernel_launch(void* const* d_in, const int* in_sizes, int n_in,
                              void* d_out, int out_size, void* d_ws, size_t ws_size,
                              hipStream_t stream)
{
    const float* x  = (const float*)d_in[0];
    const float* W  = (const float*)d_in[1];
    const float* bv = (const float*)d_in[2];
    float* out = (float*)d_out;

    bf16_t* Bm  = (bf16_t*)d_ws;                              // 1152*1152 bf16 = 2.65 MB
    float* bias = (float*)((char*)d_ws + (size_t)KDIM * NDIM * sizeof(bf16_t));

    build_wb<<<576, 256, 0, stream>>>(W, bv, Bm, bias);
    ind_gemm<<<1536, 256, 0, stream>>>(x, Bm, bias, out);
}